// Round 2
// baseline (327.185 us; speedup 1.0000x reference)
//
#include <hip/hip_runtime.h>

#define NN  2048
#define SEG 32            // elements per lane
#define QPS 8             // float4 quads per segment
#define QPR (NN / 4)      // 512 quads per row
#define WPB 4             // waves per block (256 threads)
#define RPW 2             // rows per wave

// One WAVE per row, via affine-carry suffix scan (same math as round 1, PASSED).
// New: all global traffic goes through a swizzled LDS transpose so every
// global load/store is a full-cache-line coalesced dwordx4, and `w` streams
// from LDS (never resident in regs -> no compiler rematerialization of x).
//
// LDS layout per wave: 512 quads; logical quad m stored at position
// sigma(m) = m ^ ((m>>3)&7)   (involution; permutes quads WITHIN one 128-B
// line, so global coalescing is untouched; makes segment reads [lane*8+q]
// and transpose accesses <=2-way bank conflicts).
__global__ __launch_bounds__(256, 4) void ring_givens_scan_kernel(
        const float* __restrict__ x,
        const float* __restrict__ angles,
        float* __restrict__ y,
        int B) {
    __shared__ float4 lds[WPB][QPR];    // 4 x 8 KB = 32 KB/block
    const int lane = threadIdx.x & 63;
    const int wib  = threadIdx.x >> 6;
    float4* wl = lds[wib];

    // per-lane (c,s) for k = lane*SEG + j   (amortized over RPW rows)
    float c[SEG], s[SEG];
    {
        const float* ap = angles + lane * SEG;
        #pragma unroll
        for (int j = 0; j < SEG; j += 4) {
            float4 av = *(const float4*)(ap + j);
            sincosf(av.x, &s[j    ], &c[j    ]);
            sincosf(av.y, &s[j + 1], &c[j + 1]);
            sincosf(av.z, &s[j + 2], &c[j + 2]);
            sincosf(av.w, &s[j + 3], &c[j + 3]);
        }
    }
    float sl, cl;                        // cs[NN-1] for t0
    sincosf(angles[NN - 1], &sl, &cl);

    const int gwid        = blockIdx.x * WPB + wib;
    const int total_waves = gridDim.x * WPB;

    for (int r = 0; r < RPW; ++r) {
        const int row = gwid + r * total_waves;
        if (row >= B) break;
        const float4* __restrict__ xr4 = (const float4*)(x + (size_t)row * NN);
        float4*       __restrict__ yr4 = (float4*)      (y + (size_t)row * NN);

        // --- transpose-in: coalesced full-line loads, swizzled LDS writes ---
        #pragma unroll
        for (int t = 0; t < 8; ++t) {
            const int p = t * 64 + lane;
            float4 v = xr4[p];
            wl[p ^ ((p >> 3) & 7)] = v;
        }
        asm volatile("s_waitcnt lgkmcnt(0)" ::: "memory");

        // x[0], x[2047]: broadcast LDS reads (quad 0 at pos 0; quad 511 at pos 504)
        const float x0v = ((const float*)wl)[0];
        const float xlv = ((const float*)wl)[504 * 4 + 3];
        const float t0  = sl * xlv + cl * x0v;     // v[0] after step n-1
        if (lane == 0) ((float*)wl)[0] = t0;       // patch elem 0 so both passes see t0
        asm volatile("s_waitcnt lgkmcnt(0)" ::: "memory");

        // --- pass 1: lane-local affine map (U, M), j = 31..0, w streamed from LDS ---
        float U = 0.0f, Mm = 1.0f;
        #pragma unroll
        for (int q = QPS - 1; q >= 0; --q) {
            float4 v = wl[lane * QPS + (q ^ (lane & 7))];
            const int j0 = 4 * q;
            U = c[j0 + 3] * v.w - s[j0 + 3] * U;  Mm = -s[j0 + 3] * Mm;
            U = c[j0 + 2] * v.z - s[j0 + 2] * U;  Mm = -s[j0 + 2] * Mm;
            U = c[j0 + 1] * v.y - s[j0 + 1] * U;  Mm = -s[j0 + 1] * Mm;
            U = c[j0    ] * v.x - s[j0    ] * U;  Mm = -s[j0    ] * Mm;
        }

        // --- Kogge-Stone suffix scan: S_l = F_l o F_{l+1} o ... o F_63 ---
        #pragma unroll
        for (int d = 1; d < 64; d <<= 1) {
            float Uo = __shfl_down(U, d);
            float Mo = __shfl_down(Mm, d);
            if (lane + d < 64) {
                U  = U + Mm * Uo;
                Mm = Mm * Mo;
            }
        }
        float Un = __shfl_down(U, 1);
        float Mn = __shfl_down(Mm, 1);
        float a  = (lane == 63) ? x0v : (Un + Mn * x0v);   // incoming carry

        // --- pass 2: emit outputs; quad-assembled swizzled LDS writes ---
        const int segq = lane * QPS;
        float e31 = 0.0f, p0 = 0.0f, p1 = 0.0f, p2 = 0.0f;
        #pragma unroll
        for (int q = QPS - 1; q >= 0; --q) {
            float4 v = wl[segq + (q ^ (lane & 7))];
            const int j0 = 4 * q;
            float e3 = s[j0 + 3] * v.w + c[j0 + 3] * a;  a = c[j0 + 3] * v.w - s[j0 + 3] * a;
            float e2 = s[j0 + 2] * v.z + c[j0 + 2] * a;  a = c[j0 + 2] * v.z - s[j0 + 2] * a;
            float e1 = s[j0 + 1] * v.y + c[j0 + 1] * a;  a = c[j0 + 1] * v.y - s[j0 + 1] * a;
            float e0 = s[j0    ] * v.x + c[j0    ] * a;  a = c[j0    ] * v.x - s[j0    ] * a;
            if (q == QPS - 1) {
                e31 = e3;                         // crosses to lane+1 slot 0
            } else {
                // out-quad q+1 = slots 4q+4..4q+7 = [e(4q+3), e(4q+4), e(4q+5), e(4q+6)]
                wl[segq + ((q + 1) ^ (lane & 7))] = make_float4(e3, p0, p1, p2);
            }
            p0 = e0; p1 = e1; p2 = e2;
        }
        // out-quad 0 = [slot0, e(0), e(1), e(2)]; slot0 = prev lane's e31, or y[0]=a for lane 0
        float prev = __shfl_up(e31, 1);
        float s0   = (lane == 0) ? a : prev;      // lane 63's e31 (= t0) is discarded
        wl[segq + (0 ^ (lane & 7))] = make_float4(s0, p0, p1, p2);
        asm volatile("s_waitcnt lgkmcnt(0)" ::: "memory");

        // --- transpose-out: swizzled LDS reads, coalesced full-line stores ---
        #pragma unroll
        for (int t = 0; t < 8; ++t) {
            const int p = t * 64 + lane;
            float4 v = wl[p ^ ((p >> 3) & 7)];
            yr4[p] = v;
        }
    }
}

extern "C" void kernel_launch(void* const* d_in, const int* in_sizes, int n_in,
                              void* d_out, int out_size, void* d_ws, size_t ws_size,
                              hipStream_t stream) {
    const float* x      = (const float*)d_in[0];
    const float* angles = (const float*)d_in[1];
    float* y            = (float*)d_out;

    const int B = in_sizes[0] / NN;                        // rows (16384)
    const int total_waves = (B + RPW - 1) / RPW;           // 8192
    const int blocks = (total_waves + WPB - 1) / WPB;      // 2048 blocks x 256 thr
    hipLaunchKernelGGL(ring_givens_scan_kernel, dim3(blocks), dim3(256), 0, stream,
                       x, angles, y, B);
}

// Round 3
// 249.320 us; speedup vs baseline: 1.3123x; 1.3123x over previous
//
#include <hip/hip_runtime.h>
#include <stdint.h>

#define NN  2048
#define SEG 32            // elements per lane
#define QPS 8             // float4 quads per lane segment
#define QPR 512           // quads per row
#define WPB 8             // waves per block (512 threads)
#define RPW 4             // rows per wave

#define GLOBAL_AS __attribute__((address_space(1)))
#define LDS_AS    __attribute__((address_space(3)))

// One WAVE per row via affine-carry suffix scan (math identical to rounds 1-2, PASSED).
// Round-3 changes (all data-movement, no math change):
//  - (c,s) table in LDS (shared per block, b128-readable transposed layout)
//    -> no per-thread arrays -> no scratch spill (round 2: 64-VGPR alloc spilled
//       c/s to scratch = +380 MB of HBM traffic).
//  - all row-independent scan state (Mseg, per-step scan multipliers, Mn) hoisted.
//  - transpose-in via global_load_lds w/ pre-swizzled global source (linear LDS
//    dest + swizzled read = same involution, rule both-sides-or-neither).
// LDS data layout: content[pos] = logical quad sigma(pos), sigma(m) = m ^ ((m>>3)&7)
// (involution; permutes 16B quads within one 128B line -> global coalescing kept).
__global__ __launch_bounds__(512, 4) void ring_givens_scan_kernel(
        const float* __restrict__ x,
        const float* __restrict__ angles,
        float* __restrict__ y,
        int B) {
    __shared__ float4 csT2[SEG / 2][64];   // 16 KB: [j>>1][lane] = (c_j,s_j,c_{j+1},s_{j+1}), j even
    __shared__ float4 buf[WPB][QPR];       // 64 KB data
    const int tid  = threadIdx.x;
    const int lane = tid & 63;
    const int wib  = tid >> 6;
    float4* wl = buf[wib];

    // --- build cs table: thread t computes angles 4t..4t+3 (two b128 LDS writes) ---
    {
        float4 av = ((const float4*)angles)[tid];
        float c0, s0, c1, s1, c2, s2, c3, s3;
        sincosf(av.x, &s0, &c0);
        sincosf(av.y, &s1, &c1);
        sincosf(av.z, &s2, &c2);
        sincosf(av.w, &s3, &c3);
        csT2[2 * (tid & 7)    ][tid >> 3] = make_float4(c0, s0, c1, s1);
        csT2[2 * (tid & 7) + 1][tid >> 3] = make_float4(c2, s2, c3, s3);
    }
    __syncthreads();

    const float4 csE = csT2[15][63];       // (c,s) for k=2047 in .z/.w (broadcast)
    const float cl = csE.z, sl = csE.w;

    // --- row-independent scan state (angles only), once per wave ---
    float Mseg = 1.0f;                     // prod of (-s_j) over 32 j = prod s_j
    #pragma unroll
    for (int q = 0; q < QPS; ++q) {
        float4 A  = csT2[2 * q    ][lane];
        float4 Bq = csT2[2 * q + 1][lane];
        Mseg *= (A.y * A.w) * (Bq.y * Bq.w);
    }
    float Ms[6];
    float Mc = Mseg;
    #pragma unroll
    for (int d = 1, st = 0; d < 64; d <<= 1, ++st) {
        Ms[st] = (lane + d < 64) ? Mc : 0.0f;   // predicate folded into multiplier
        float Mo = __shfl_down(Mc, d);
        if (lane + d < 64) Mc = Mc * Mo;
    }
    float Mn = __shfl_down(Mc, 1);
    Mn = (lane == 63) ? 1.0f : Mn;              // lane 63 carry = x0 directly

    const int gwid        = blockIdx.x * WPB + wib;
    const int total_waves = gridDim.x * WPB;

    for (int r = 0; r < RPW; ++r) {
        const int row = gwid + r * total_waves;
        if (row >= B) break;
        const float4* __restrict__ xr4 = (const float4*)(x + (size_t)row * NN);
        float4*       __restrict__ yr4 = (float4*)      (y + (size_t)row * NN);

        // --- transpose-in: global_load_lds, linear LDS dest, swizzled global src ---
        #pragma unroll
        for (int t = 0; t < 8; ++t) {
            const int srcq = (t * 64 + lane) ^ ((lane >> 3) & 7);
            __builtin_amdgcn_global_load_lds(
                (const GLOBAL_AS uint32_t*)(const void*)(xr4 + srcq),
                (LDS_AS uint32_t*)(void*)(wl + t * 64), 16, 0, 0);
        }
        asm volatile("s_waitcnt vmcnt(0)" ::: "memory");

        // x[0] at pos word 0; x[2047] at logical quad 511 -> pos 504, word 3
        const float x0v = ((const float*)wl)[0];
        const float xlv = ((const float*)wl)[504 * 4 + 3];
        const float t0  = sl * xlv + cl * x0v;       // v[0] after step n-1
        if (lane == 0) ((float*)wl)[0] = t0;         // both passes consume t0 at k=0

        // --- pass 1: U only (M hoisted), j = 31..0 streamed from LDS ---
        float U = 0.0f;
        #pragma unroll
        for (int q = QPS - 1; q >= 0; --q) {
            float4 v  = wl[lane * QPS + (q ^ (lane & 7))];
            float4 A  = csT2[2 * q    ][lane];
            float4 Bq = csT2[2 * q + 1][lane];
            U = Bq.z * v.w - Bq.w * U;
            U = Bq.x * v.z - Bq.y * U;
            U = A.z  * v.y - A.w  * U;
            U = A.x  * v.x - A.y  * U;
        }

        // --- suffix scan, U-part only ---
        #pragma unroll
        for (int d = 1, st = 0; d < 64; d <<= 1, ++st) {
            float Uo = __shfl_down(U, d);
            U = fmaf(Ms[st], Uo, U);
        }
        float Un = __shfl_down(U, 1);
        Un = (lane == 63) ? 0.0f : Un;
        float a = fmaf(Mn, x0v, Un);                 // incoming carry per lane

        // --- pass 2: emit outputs, quad-assembled swizzled LDS writes ---
        const int segq = lane * QPS;
        float e31, p0, p1, p2;
        {   // q = 7
            float4 v  = wl[segq + (7 ^ (lane & 7))];
            float4 A  = csT2[14][lane];
            float4 Bq = csT2[15][lane];
            e31 = Bq.w * v.w + Bq.z * a;  a = Bq.z * v.w - Bq.w * a;
            p2  = Bq.y * v.z + Bq.x * a;  a = Bq.x * v.z - Bq.y * a;
            p1  = A.w  * v.y + A.z  * a;  a = A.z  * v.y - A.w  * a;
            p0  = A.y  * v.x + A.x  * a;  a = A.x  * v.x - A.y  * a;
        }
        #pragma unroll
        for (int q = QPS - 2; q >= 0; --q) {
            float4 v  = wl[segq + (q ^ (lane & 7))];
            float4 A  = csT2[2 * q    ][lane];
            float4 Bq = csT2[2 * q + 1][lane];
            float e3 = Bq.w * v.w + Bq.z * a;  a = Bq.z * v.w - Bq.w * a;
            // out-quad q+1 = [e(4q+3), e(4q+4), e(4q+5), e(4q+6)]
            wl[segq + ((q + 1) ^ (lane & 7))] = make_float4(e3, p0, p1, p2);
            float e2 = Bq.y * v.z + Bq.x * a;  a = Bq.x * v.z - Bq.y * a;
            float e1 = A.w  * v.y + A.z  * a;  a = A.z  * v.y - A.w  * a;
            float e0 = A.y  * v.x + A.x  * a;  a = A.x  * v.x - A.y  * a;
            p0 = e0; p1 = e1; p2 = e2;
        }
        float prev = __shfl_up(e31, 1);
        float s0v  = (lane == 0) ? a : prev;         // lane0 slot0 = y[0] = final carry
        wl[segq + (0 ^ (lane & 7))] = make_float4(s0v, p0, p1, p2);

        // --- transpose-out: swizzled LDS reads, perfectly linear global stores ---
        #pragma unroll
        for (int t = 0; t < 8; ++t) {
            const int p = t * 64 + lane;
            float4 v = wl[p ^ ((lane >> 3) & 7)];
            yr4[p] = v;
        }
        // drain LDS reads before next row's global_load_lds overwrites the buffer
        asm volatile("s_waitcnt lgkmcnt(0)" ::: "memory");
    }
}

extern "C" void kernel_launch(void* const* d_in, const int* in_sizes, int n_in,
                              void* d_out, int out_size, void* d_ws, size_t ws_size,
                              hipStream_t stream) {
    const float* x      = (const float*)d_in[0];
    const float* angles = (const float*)d_in[1];
    float* y            = (float*)d_out;

    const int B = in_sizes[0] / NN;                        // rows (16384)
    const int total_waves = (B + RPW - 1) / RPW;           // 4096
    const int blocks = (total_waves + WPB - 1) / WPB;      // 512 blocks x 512 thr
    hipLaunchKernelGGL(ring_givens_scan_kernel, dim3(blocks), dim3(512), 0, stream,
                       x, angles, y, B);
}

// Round 4
// 238.239 us; speedup vs baseline: 1.3733x; 1.0465x over previous
//
#include <hip/hip_runtime.h>
#include <stdint.h>

#define NN  2048
#define QPS 8             // float4 quads per lane segment
#define QPR 512           // quads per row
#define WPB 4             // waves per block (256 threads)
#define RPW 8             // rows per wave

#define GLOBAL_AS __attribute__((address_space(1)))
#define LDS_AS    __attribute__((address_space(3)))

// One WAVE per row via affine-carry suffix scan (math identical to rounds 1-3, PASSED).
// Round-4: software-pipelined rows. Per-wave DOUBLE LDS buffer; next row's
// global_load_lds issued at row start (T14 issue-early), counted vmcnt(8)
// instead of a full drain (T4); x kept in VGPRs after pass-1 (pass-2 reads
// regs); (c,s) table lives in VGPRs (built once/wave) -> per-row LDS ops
// drop 64 -> 32 and the ~900-cycle HBM drain is hidden under compute.
// LDS layout: content[pos] = logical quad sigma(pos), sigma(m)=m^((m>>3)&7)
// (involution inside each 128-B line; global coalescing untouched).
__global__ __launch_bounds__(256, 2) void ring_givens_scan_kernel(
        const float* __restrict__ x,
        const float* __restrict__ angles,
        float* __restrict__ y,
        int B) {
    __shared__ float4 buf[WPB][2][QPR];      // 4 waves x 2 x 8 KB = 64 KB
    const int lane = threadIdx.x & 63;
    const int wib  = threadIdx.x >> 6;
    float4* b0 = buf[wib][0];
    float4* b1 = buf[wib][1];

    // --- per-lane (c,s) in REGISTERS: A[q]=(c,s,c,s) for j=4q,4q+1; Bq[q] for 4q+2,4q+3 ---
    float4 A[QPS], Bq[QPS];
    {
        const float4* ap4 = (const float4*)(angles + lane * 32);
        #pragma unroll
        for (int q = 0; q < QPS; ++q) {
            float4 av = ap4[q];
            float ss, cc;
            sincosf(av.x, &ss, &cc); A[q].x = cc;  A[q].y = ss;
            sincosf(av.y, &ss, &cc); A[q].z = cc;  A[q].w = ss;
            sincosf(av.z, &ss, &cc); Bq[q].x = cc; Bq[q].y = ss;
            sincosf(av.w, &ss, &cc); Bq[q].z = cc; Bq[q].w = ss;
        }
    }
    float sl, cl;                            // (c,s) for k = 2047 (t0 fold)
    sincosf(angles[NN - 1], &sl, &cl);

    // --- row-independent scan state: Mseg, per-step multipliers, carry mult ---
    float Mseg = 1.0f;
    #pragma unroll
    for (int q = 0; q < QPS; ++q)
        Mseg *= (A[q].y * A[q].w) * (Bq[q].y * Bq[q].w);
    float Ms[6];
    float Mc = Mseg;
    #pragma unroll
    for (int d = 1, st = 0; d < 64; d <<= 1, ++st) {
        Ms[st] = (lane + d < 64) ? Mc : 0.0f;     // predicate folded in
        float Mo = __shfl_down(Mc, d);
        if (lane + d < 64) Mc = Mc * Mo;
    }
    float Mn = __shfl_down(Mc, 1);
    Mn = (lane == 63) ? 1.0f : Mn;                // lane 63 carry = x0 directly

    const int gwid        = blockIdx.x * WPB + wib;
    const int total_waves = gridDim.x * WPB;

    // --- prologue: issue row 0 loads into b0 (swizzled global src, linear LDS dest) ---
    if (gwid < B) {
        const float4* xr4 = (const float4*)(x + (size_t)gwid * NN);
        #pragma unroll
        for (int t = 0; t < 8; ++t) {
            const int srcq = (t * 64 + lane) ^ ((lane >> 3) & 7);
            __builtin_amdgcn_global_load_lds(
                (const GLOBAL_AS uint32_t*)(const void*)(xr4 + srcq),
                (LDS_AS uint32_t*)(void*)(b0 + t * 64), 16, 0, 0);
        }
    }

    for (int r = 0; r < RPW; ++r) {
        const int row = gwid + r * total_waves;
        if (row >= B) break;
        float4* P = (r & 1) ? b1 : b0;            // this row's data (loads in flight)
        float4* Q = (r & 1) ? b0 : b1;            // next row's landing zone

        // wait for THIS row's 8 loads; leave stores(r-1) in flight (counted vmcnt)
        if (r == 0) asm volatile("s_waitcnt vmcnt(0)" ::: "memory");
        else        asm volatile("s_waitcnt vmcnt(8)" ::: "memory");

        // issue NEXT row's loads immediately -> in flight under this row's compute
        const int nrow = row + total_waves;
        if (r + 1 < RPW && nrow < B) {
            const float4* xn4 = (const float4*)(x + (size_t)nrow * NN);
            #pragma unroll
            for (int t = 0; t < 8; ++t) {
                const int srcq = (t * 64 + lane) ^ ((lane >> 3) & 7);
                __builtin_amdgcn_global_load_lds(
                    (const GLOBAL_AS uint32_t*)(const void*)(xn4 + srcq),
                    (LDS_AS uint32_t*)(void*)(Q + t * 64), 16, 0, 0);
            }
        }

        // --- pass 1 input: segment -> regs (8 x ds_read_b128, conflict-free) ---
        const int segq = lane * QPS;
        float4 w4[QPS];
        #pragma unroll
        for (int q = 0; q < QPS; ++q)
            w4[q] = P[segq + (q ^ (lane & 7))];

        // ring boundary: x[0], x[2047] via shfl; lane 0 patches t0 into its reg
        const float x0v = __shfl(w4[0].x, 0);
        const float xlv = __shfl(w4[7].w, 63);
        const float t0  = sl * xlv + cl * x0v;
        if (lane == 0) w4[0].x = t0;

        // --- pass 1: lane-local U (M hoisted), j = 31..0 ---
        float U = 0.0f;
        #pragma unroll
        for (int q = QPS - 1; q >= 0; --q) {
            U = Bq[q].z * w4[q].w - Bq[q].w * U;
            U = Bq[q].x * w4[q].z - Bq[q].y * U;
            U = A[q].z  * w4[q].y - A[q].w  * U;
            U = A[q].x  * w4[q].x - A[q].y  * U;
        }

        // --- suffix scan (U only) ---
        #pragma unroll
        for (int d = 1, st = 0; d < 64; d <<= 1, ++st) {
            float Uo = __shfl_down(U, d);
            U = fmaf(Ms[st], Uo, U);
        }
        float Un = __shfl_down(U, 1);
        Un = (lane == 63) ? 0.0f : Un;
        float a = fmaf(Mn, x0v, Un);              // incoming carry

        // --- pass 2: emit from regs, quad-assembled swizzled LDS writes -> P ---
        float e31, p0, p1, p2;
        {   // q = 7
            float4 v = w4[7];
            e31 = Bq[7].w * v.w + Bq[7].z * a;  a = Bq[7].z * v.w - Bq[7].w * a;
            p2  = Bq[7].y * v.z + Bq[7].x * a;  a = Bq[7].x * v.z - Bq[7].y * a;
            p1  = A[7].w  * v.y + A[7].z  * a;  a = A[7].z  * v.y - A[7].w  * a;
            p0  = A[7].y  * v.x + A[7].x  * a;  a = A[7].x  * v.x - A[7].y  * a;
        }
        #pragma unroll
        for (int q = QPS - 2; q >= 0; --q) {
            float4 v = w4[q];
            float e3 = Bq[q].w * v.w + Bq[q].z * a;  a = Bq[q].z * v.w - Bq[q].w * a;
            P[segq + ((q + 1) ^ (lane & 7))] = make_float4(e3, p0, p1, p2);
            float e2 = Bq[q].y * v.z + Bq[q].x * a;  a = Bq[q].x * v.z - Bq[q].y * a;
            float e1 = A[q].w  * v.y + A[q].z  * a;  a = A[q].z  * v.y - A[q].w  * a;
            float e0 = A[q].y  * v.x + A[q].x  * a;  a = A[q].x  * v.x - A[q].y  * a;
            p0 = e0; p1 = e1; p2 = e2;
        }
        float prev = __shfl_up(e31, 1);
        float s0v  = (lane == 0) ? a : prev;      // lane0 slot0 = y[0] = final carry
        P[segq + (0 ^ (lane & 7))] = make_float4(s0v, p0, p1, p2);

        // --- transpose-out: swizzled LDS reads, linear coalesced global stores ---
        float4* __restrict__ yr4 = (float4*)(y + (size_t)row * NN);
        #pragma unroll
        for (int t = 0; t < 8; ++t) {
            const int p = t * 64 + lane;
            float4 v = P[p ^ ((lane >> 3) & 7)];
            yr4[p] = v;
        }
    }
}

extern "C" void kernel_launch(void* const* d_in, const int* in_sizes, int n_in,
                              void* d_out, int out_size, void* d_ws, size_t ws_size,
                              hipStream_t stream) {
    const float* x      = (const float*)d_in[0];
    const float* angles = (const float*)d_in[1];
    float* y            = (float*)d_out;

    const int B = in_sizes[0] / NN;                        // rows (16384)
    const int total_waves = (B + RPW - 1) / RPW;           // 2048
    const int blocks = (total_waves + WPB - 1) / WPB;      // 512 blocks x 256 thr
    hipLaunchKernelGGL(ring_givens_scan_kernel, dim3(blocks), dim3(256), 0, stream,
                       x, angles, y, B);
}